// Round 7
// baseline (321.657 us; speedup 1.0000x reference)
//
#include <hip/hip_runtime.h>
#include <math.h>

#define B_ 64
#define I_ 4096
#define P_ 8      // Din
#define N_ 10
#define D_ 16
#define ND_ 160   // N*D
#define BND_ (B_*ND_)   // 10240
#define EPS_ 1e-7f

// Round-7 structure: lane = b (64 lanes = 64 batch elements), wave = one i at a
// time, block = 320 threads = 5 waves, wave w owns n-pair {2w, 2w+1}.
//  - W[i, n, p, :] addresses are wave-uniform -> compiler emits s_load (SMEM);
//    the inner loops are pure v_fmac with one SGPR operand. NO cross-lane ops,
//    NO DS-pipe reductions (rounds 4/6 proved bpermute/DPP reductions are the
//    bottleneck: occupancy-insensitive ~26 us/pass of DS/hazard serialization).
//  - One sweep: u_hat pair tv[2][16] stays in 32 VGPRs, reused for logit dot
//    (in-thread, 16 FMA) and weighted accumulation. No recompute.
//  - Cross-wave softmax exchange: 2 floats/thread via 5.6 KB double-buffered
//    LDS table, 1 barrier per il (dbuf makes write(il+1)/read(il) safe).
// __launch_bounds__(320) only — do NOT add a waves/EU bound (round 3: forcing
// occupancy caused 350 MB/pass scratch spill).
template<int MODE, int IPB>
__global__ __launch_bounds__(320)
void digitcaps_pass(const float* __restrict__ x, const float* __restrict__ W,
                    const float* __restrict__ Vc, float* __restrict__ part)
{
    __shared__ float lgsh[2][B_][N_ + 1];   // +1 pad: stride 11 (odd) -> conflict-free
    const int t = threadIdx.x;
    const int b = t & 63;
    const int w = t >> 6;          // 0..4
    const int n0 = 2 * w;

    float vc[2][D_];
    if (MODE == 1) {
        // hoisted once per kernel; uncoalesced but 8 instr total
#pragma unroll
        for (int q = 0; q < 2; ++q)
#pragma unroll
            for (int d4 = 0; d4 < 4; ++d4) {
                float4 vv = *(const float4*)(Vc + b * ND_ + (n0 + q) * D_ + d4 * 4);
                vc[q][d4 * 4 + 0] = vv.x; vc[q][d4 * 4 + 1] = vv.y;
                vc[q][d4 * 4 + 2] = vv.z; vc[q][d4 * 4 + 3] = vv.w;
            }
    }

    float acc[2][D_];
#pragma unroll
    for (int q = 0; q < 2; ++q)
#pragma unroll
        for (int d = 0; d < D_; ++d) acc[q][d] = 0.f;

    const int i0 = blockIdx.x * IPB;

#pragma unroll 1
    for (int il = 0; il < IPB; ++il) {
        const int i = i0 + il;
        float xv[P_];
        {
            const float4* xp = (const float4*)(x + ((size_t)b * I_ + i) * P_);
            float4 a0 = xp[0], a1 = xp[1];
            xv[0]=a0.x; xv[1]=a0.y; xv[2]=a0.z; xv[3]=a0.w;
            xv[4]=a1.x; xv[5]=a1.y; xv[6]=a1.z; xv[7]=a1.w;
        }
        // wave-uniform W base for this wave's n-pair
        const float* __restrict__ Wi = W + (size_t)i * (N_ * P_ * D_) + n0 * (P_ * D_);

        // one sweep: u_hat pair into registers (wave-uniform W -> SGPR operand)
        float tv[2][D_];
#pragma unroll
        for (int q = 0; q < 2; ++q) {
            const float* __restrict__ Wn = Wi + q * (P_ * D_);
#pragma unroll
            for (int d = 0; d < D_; ++d) tv[q][d] = 0.f;
#pragma unroll
            for (int p = 0; p < P_; ++p)
#pragma unroll
                for (int d = 0; d < D_; ++d)
                    tv[q][d] = fmaf(Wn[p * D_ + d], xv[p], tv[q][d]);
        }

        if (MODE == 0) {
            // uniform c (softmax of zeros) -> 0.1 scale applied in reduce
#pragma unroll
            for (int q = 0; q < 2; ++q)
#pragma unroll
                for (int d = 0; d < D_; ++d) acc[q][d] += tv[q][d];
        } else {
            float lgq[2];
#pragma unroll
            for (int q = 0; q < 2; ++q) {
                float lA = 0.f, lB = 0.f;
#pragma unroll
                for (int d = 0; d < 8; ++d) {
                    lA = fmaf(tv[q][d], vc[q][d], lA);
                    lB = fmaf(tv[q][d + 8], vc[q][d + 8], lB);
                }
                lgq[q] = lA + lB;
            }
            const int buf = il & 1;
            lgsh[buf][b][n0]     = lgq[0];
            lgsh[buf][b][n0 + 1] = lgq[1];
            __syncthreads();
            float lg[N_];
#pragma unroll
            for (int n = 0; n < N_; ++n) lg[n] = lgsh[buf][b][n];
            float m = lg[0];
#pragma unroll
            for (int n = 1; n < N_; ++n) m = fmaxf(m, lg[n]);
            float se = 0.f;
#pragma unroll
            for (int n = 0; n < N_; ++n) se += __expf(lg[n] - m);
            float inv = 1.f / se;
            float cq[2];
            cq[0] = __expf(lgq[0] - m) * inv;
            cq[1] = __expf(lgq[1] - m) * inv;
#pragma unroll
            for (int q = 0; q < 2; ++q)
#pragma unroll
                for (int d = 0; d < D_; ++d)
                    acc[q][d] = fmaf(cq[q], tv[q][d], acc[q][d]);
        }
    }

    // store partials transposed [blk][nd][b]: lanes b contiguous -> coalesced
    float* __restrict__ po = part + (size_t)blockIdx.x * BND_;
#pragma unroll
    for (int q = 0; q < 2; ++q)
#pragma unroll
        for (int d = 0; d < D_; ++d)
            po[((n0 + q) * D_ + d) * B_ + b] = acc[q][d];
}

// Parallel-wide reduce over part rows (layout [row][nd*64+b]). Block handles
// 16 k-values; 16 threads per k sum rows/16 partials with coalesced loads.
__global__ __launch_bounds__(256)
void digitcaps_reduce(const float* __restrict__ part, int rows,
                      float scale, int mode,
                      float* __restrict__ Vc, float* __restrict__ out)
{
    __shared__ float sm[4][16];
    const int t = threadIdx.x;
    const int kk = t & 15;
    const int tp = t >> 4;                // 0..15
    const int k = blockIdx.x * 16 + kk;

    float s = 0.f;
    const int steps = rows >> 4;          // rows/16 per tp-thread
    const float* __restrict__ p0 = part + (size_t)tp * BND_ + k;
    const size_t stride = (size_t)16 * BND_;
#pragma unroll 8
    for (int j = 0; j < steps; ++j)
        s += p0[(size_t)j * stride];

    s += __shfl_down(s, 32);
    s += __shfl_down(s, 16);
    if ((t & 63) < 16) sm[t >> 6][kk] = s;
    __syncthreads();

    if (t < 16) {
        float tot = (sm[0][t] + sm[1][t]) + (sm[2][t] + sm[3][t]);
        tot *= scale;
        float sq = tot * tot;
        float v = tot * (sq / ((1.f + sq) * sqrtf(sq + EPS_)));
        int k2 = blockIdx.x * 16 + t;     // k2 = nd*64 + b (partial layout)
        int j = (k2 & 63) * ND_ + (k2 >> 6);   // natural [b][n][d] layout
        if (mode == 0)      Vc[j] = v;        // after iter 0: Vc = v0
        else if (mode == 1) Vc[j] += v;       // after iter 1: Vc = v0 + v1
        else                out[j] = v;       // final output [B,N,1,D]
    }
}

extern "C" void kernel_launch(void* const* d_in, const int* in_sizes, int n_in,
                              void* d_out, int out_size, void* d_ws, size_t ws_size,
                              hipStream_t stream)
{
    const float* x = (const float*)d_in[0];   // [64, 4096, 8] f32
    const float* W = (const float*)d_in[1];   // [4096, 10, 8, 16] f32
    float* out = (float*)d_out;               // [64, 10, 1, 16] f32

    // rows = pass grid size = partial width. 1024 (IPB=4, proven ws fit in
    // rounds 3-6) preferred; 512 fallback.
    size_t need1024 = ((size_t)1024 * BND_ + BND_) * sizeof(float);
    int rows = (ws_size >= need1024) ? 1024 : 512;

    float* part = (float*)d_ws;
    float* Vc   = part + (size_t)rows * BND_;

    dim3 pblk(320), grid(rows), rblk(256), rgrid(BND_ / 16);

    for (int pass = 0; pass < 3; ++pass) {
        if (rows == 1024) {
            if (pass == 0)
                digitcaps_pass<0, 4><<<grid, pblk, 0, stream>>>(x, W, nullptr, part);
            else
                digitcaps_pass<1, 4><<<grid, pblk, 0, stream>>>(x, W, Vc, part);
        } else {
            if (pass == 0)
                digitcaps_pass<0, 8><<<grid, pblk, 0, stream>>>(x, W, nullptr, part);
            else
                digitcaps_pass<1, 8><<<grid, pblk, 0, stream>>>(x, W, Vc, part);
        }
        digitcaps_reduce<<<rgrid, rblk, 0, stream>>>(part, rows,
                                                     pass == 0 ? 0.1f : 1.0f, pass, Vc, out);
    }
}

// Round 8
// 186.884 us; speedup vs baseline: 1.7212x; 1.7212x over previous
//
#include <hip/hip_runtime.h>
#include <math.h>

#define B_ 64
#define I_ 4096
#define P_ 8      // Din
#define N_ 10
#define D_ 16
#define ND_ 160   // N*D
#define BND_ (B_*ND_)   // 10240
#define EPS_ 1e-7f

#define IPB_ 8                 // i per block
#define ROWS_ (I_ / IPB_)      // 512 blocks
#define WTILE_ (N_ * P_ * D_)  // 1280 floats of W per i
#define LGS_ 11                // padded logit row stride (odd -> bank-clean)

// Transpose x [B,I,P] -> xT [I,B,P] so the pass kernel's per-(i,wave) x read
// is a contiguous 2 KB coalesced segment (lane b reads 32 B at stride 32 B).
__global__ __launch_bounds__(256)
void xT_kernel(const float* __restrict__ x, float* __restrict__ xT)
{
    int idx = blockIdx.x * 256 + threadIdx.x;     // 64*4096*8 = 2,097,152
    int p = idx & 7;
    int i = (idx >> 3) & (I_ - 1);
    int b = idx >> 15;
    xT[((size_t)i * B_ + b) * P_ + p] = x[idx];   // read coalesced, write 32B chunks
}

// Round-8 structure (R7 dataflow + LDS W delivery):
//  - lane = b (64 batch), block = 320 thr = 5 waves, wave w owns n-pair {2w,2w+1}.
//  - W slice for the block's 8 i (40 KB) is staged into LDS ONCE (coalesced
//    float4 copy + 1 barrier). Inner-loop W reads are ds_read_b128 with
//    wave-uniform addresses = LDS broadcast (conflict-free) — this replaces
//    R7's global W loads whose L2/L3 latency pinned VALUBusy at 12%.
//  - u_hat pair tv[2][16] in regs, single sweep; logit dot in-thread (zero
//    cross-lane reductions — R2/R4/R6 proved shuffle/DPP trees are the wall).
//  - softmax exchange: 2 floats/thread via double-buffered lgsh, 1 barrier/il.
//  - x for il+1 is prefetched BEFORE the barrier: __syncthreads drains vmcnt,
//    so the value is register-resident when needed (free prefetch fence).
// __launch_bounds__(320) only — NO min-waves arg (round 3: forcing occupancy
// caused 350 MB/pass scratch spill). DO NOT tighten.
template<int MODE>
__global__ __launch_bounds__(320)
void digitcaps_pass(const float* __restrict__ xT, const float* __restrict__ W,
                    const float* __restrict__ Vc, float* __restrict__ part)
{
    __shared__ float wsh[IPB_ * WTILE_];                      // 40960 B
    __shared__ float lgsh[(MODE == 1) ? 2 : 1][B_][LGS_];     // 5632 B when used
    const int t = threadIdx.x;
    const int b = t & 63;
    const int w = t >> 6;          // 0..4
    const int n0 = 2 * w;
    const int i0 = blockIdx.x * IPB_;

    // ---- stage W[i0..i0+8) into LDS: 10240 floats = 2560 float4, 8/thread ----
    {
        const float4* __restrict__ Wg = (const float4*)(W + (size_t)i0 * WTILE_);
        float4* __restrict__ Ws = (float4*)wsh;
#pragma unroll
        for (int c = 0; c < (IPB_ * WTILE_) / 4 / 320; ++c)   // 8 chunks
            Ws[c * 320 + t] = Wg[c * 320 + t];                // coalesced; 16B/lane LDS write
    }

    float vc[2][D_];
    if (MODE == 1) {
#pragma unroll
        for (int q = 0; q < 2; ++q) {
            const float4* vp = (const float4*)(Vc + (size_t)b * ND_ + (n0 + q) * D_);
#pragma unroll
            for (int d4 = 0; d4 < 4; ++d4) {
                float4 vv = vp[d4];
                vc[q][d4 * 4 + 0] = vv.x; vc[q][d4 * 4 + 1] = vv.y;
                vc[q][d4 * 4 + 2] = vv.z; vc[q][d4 * 4 + 3] = vv.w;
            }
        }
    }

    float acc[2][D_];
#pragma unroll
    for (int q = 0; q < 2; ++q)
#pragma unroll
        for (int d = 0; d < D_; ++d) acc[q][d] = 0.f;

    // preload x for il=0
    float xv[P_];
    {
        const float4* xp = (const float4*)(xT + ((size_t)i0 * B_ + b) * P_);
        float4 a0 = xp[0], a1 = xp[1];
        xv[0]=a0.x; xv[1]=a0.y; xv[2]=a0.z; xv[3]=a0.w;
        xv[4]=a1.x; xv[5]=a1.y; xv[6]=a1.z; xv[7]=a1.w;
    }

    __syncthreads();   // W staged (also drains the xv preload)

#pragma unroll 1
    for (int il = 0; il < IPB_; ++il) {
        // u_hat pair from LDS-broadcast W reads (wave-uniform addresses)
        const float* __restrict__ Wt = wsh + il * WTILE_ + n0 * (P_ * D_);
        float tv[2][D_];
#pragma unroll
        for (int q = 0; q < 2; ++q) {
            const float* __restrict__ Wq = Wt + q * (P_ * D_);
#pragma unroll
            for (int d = 0; d < D_; ++d) tv[q][d] = 0.f;
#pragma unroll
            for (int p = 0; p < P_; ++p) {
                const float4* __restrict__ wp = (const float4*)(Wq + p * D_);
#pragma unroll
                for (int d4 = 0; d4 < 4; ++d4) {
                    float4 wv = wp[d4];                       // ds_read_b128 broadcast
                    tv[q][d4 * 4 + 0] = fmaf(wv.x, xv[p], tv[q][d4 * 4 + 0]);
                    tv[q][d4 * 4 + 1] = fmaf(wv.y, xv[p], tv[q][d4 * 4 + 1]);
                    tv[q][d4 * 4 + 2] = fmaf(wv.z, xv[p], tv[q][d4 * 4 + 2]);
                    tv[q][d4 * 4 + 3] = fmaf(wv.w, xv[p], tv[q][d4 * 4 + 3]);
                }
            }
        }

        // prefetch x for il+1 BEFORE the barrier (barrier drains vmcnt -> ready)
        float xn[P_];
        if (il + 1 < IPB_) {
            const float4* xp = (const float4*)(xT + ((size_t)(i0 + il + 1) * B_ + b) * P_);
            float4 a0 = xp[0], a1 = xp[1];
            xn[0]=a0.x; xn[1]=a0.y; xn[2]=a0.z; xn[3]=a0.w;
            xn[4]=a1.x; xn[5]=a1.y; xn[6]=a1.z; xn[7]=a1.w;
        }

        if (MODE == 0) {
            // uniform c (softmax of zeros) -> 0.1 scale applied in reduce
#pragma unroll
            for (int q = 0; q < 2; ++q)
#pragma unroll
                for (int d = 0; d < D_; ++d) acc[q][d] += tv[q][d];
        } else {
            float lgq[2];
#pragma unroll
            for (int q = 0; q < 2; ++q) {
                float lA = 0.f, lB = 0.f;
#pragma unroll
                for (int d = 0; d < 8; ++d) {
                    lA = fmaf(tv[q][d], vc[q][d], lA);
                    lB = fmaf(tv[q][d + 8], vc[q][d + 8], lB);
                }
                lgq[q] = lA + lB;
            }
            const int buf = il & 1;
            lgsh[buf][b][n0]     = lgq[0];
            lgsh[buf][b][n0 + 1] = lgq[1];
            __syncthreads();
            float lg[N_];
#pragma unroll
            for (int n = 0; n < N_; ++n) lg[n] = lgsh[buf][b][n];
            float m = lg[0];
#pragma unroll
            for (int n = 1; n < N_; ++n) m = fmaxf(m, lg[n]);
            float se = 0.f;
#pragma unroll
            for (int n = 0; n < N_; ++n) se += __expf(lg[n] - m);
            float inv = 1.f / se;
            float cq0 = __expf(lgq[0] - m) * inv;
            float cq1 = __expf(lgq[1] - m) * inv;
#pragma unroll
            for (int d = 0; d < D_; ++d) {
                acc[0][d] = fmaf(cq0, tv[0][d], acc[0][d]);
                acc[1][d] = fmaf(cq1, tv[1][d], acc[1][d]);
            }
        }

#pragma unroll
        for (int p = 0; p < P_; ++p) xv[p] = xn[p];
    }

    // store partials transposed [blk][nd][b]: lane b contiguous -> coalesced
    float* __restrict__ po = part + (size_t)blockIdx.x * BND_;
#pragma unroll
    for (int q = 0; q < 2; ++q)
#pragma unroll
        for (int d = 0; d < D_; ++d)
            po[((n0 + q) * D_ + d) * B_ + b] = acc[q][d];
}

// Parallel-wide reduce over part rows (layout [row][nd*64+b]). Block handles
// 16 k-values; 16 threads per k sum rows/16 partials with coalesced loads.
__global__ __launch_bounds__(256)
void digitcaps_reduce(const float* __restrict__ part, int rows,
                      float scale, int mode,
                      float* __restrict__ Vc, float* __restrict__ out)
{
    __shared__ float sm[4][16];
    const int t = threadIdx.x;
    const int kk = t & 15;
    const int tp = t >> 4;                // 0..15
    const int k = blockIdx.x * 16 + kk;

    float s = 0.f;
    const int steps = rows >> 4;
    const float* __restrict__ p0 = part + (size_t)tp * BND_ + k;
    const size_t stride = (size_t)16 * BND_;
#pragma unroll 8
    for (int j = 0; j < steps; ++j)
        s += p0[(size_t)j * stride];

    s += __shfl_down(s, 32);
    s += __shfl_down(s, 16);
    if ((t & 63) < 16) sm[t >> 6][kk] = s;
    __syncthreads();

    if (t < 16) {
        float tot = (sm[0][t] + sm[1][t]) + (sm[2][t] + sm[3][t]);
        tot *= scale;
        float sq = tot * tot;
        float v = tot * (sq / ((1.f + sq) * sqrtf(sq + EPS_)));
        int k2 = blockIdx.x * 16 + t;          // k2 = nd*64 + b (partial layout)
        int j = (k2 & 63) * ND_ + (k2 >> 6);   // natural [b][n][d] layout
        if (mode == 0)      Vc[j] = v;         // after iter 0: Vc = v0
        else if (mode == 1) Vc[j] += v;        // after iter 1: Vc = v0 + v1
        else                out[j] = v;        // final output [B,N,1,D]
    }
}

extern "C" void kernel_launch(void* const* d_in, const int* in_sizes, int n_in,
                              void* d_out, int out_size, void* d_ws, size_t ws_size,
                              hipStream_t stream)
{
    const float* x = (const float*)d_in[0];   // [64, 4096, 8] f32
    const float* W = (const float*)d_in[1];   // [4096, 10, 8, 16] f32
    float* out = (float*)d_out;               // [64, 10, 1, 16] f32

    // ws layout: part (512*10240 f) | Vc (10240 f) | xT (2,097,152 f) = 29.4 MB
    // (rounds 3-7 proved ws >= 42 MB, so this always fits)
    float* part = (float*)d_ws;
    float* Vc   = part + (size_t)ROWS_ * BND_;
    float* xT   = Vc + BND_;

    dim3 pblk(320), pgrid(ROWS_), rblk(256), rgrid(BND_ / 16);

    xT_kernel<<<dim3((B_ * I_ * P_) / 256), dim3(256), 0, stream>>>(x, xT);

    for (int pass = 0; pass < 3; ++pass) {
        if (pass == 0)
            digitcaps_pass<0><<<pgrid, pblk, 0, stream>>>(xT, W, nullptr, part);
        else
            digitcaps_pass<1><<<pgrid, pblk, 0, stream>>>(xT, W, Vc, part);
        digitcaps_reduce<<<rgrid, rblk, 0, stream>>>(part, ROWS_,
                                                     pass == 0 ? 0.1f : 1.0f, pass, Vc, out);
    }
}